// Round 1
// baseline (290.427 us; speedup 1.0000x reference)
//
#include <hip/hip_runtime.h>
#include <math.h>

#define N_NODES 8192
#define EDIM    256
#define HEADS   8
#define HDIM    32
#define NEDGE   262144
#define SCALING 0.17677669529663687f   // 1/sqrt(32)

// ---------------------------------------------------------------------------
// K2: Wksum[d,c] = sum_h W_in[256 + h*32 + d, c];  bksum[d] = sum_h b_in[...]
// ---------------------------------------------------------------------------
__global__ void wksum_kernel(const float* __restrict__ W_in,
                             const float* __restrict__ b_in,
                             float* __restrict__ Wksum,
                             float* __restrict__ bksum) {
    int idx = blockIdx.x * 256 + threadIdx.x;   // 8192 = 32*256
    int d = idx >> 8, c = idx & 255;
    float sum = 0.f;
    for (int h = 0; h < HEADS; ++h)
        sum += W_in[(size_t)(EDIM + h * HDIM + d) * EDIM + c];
    Wksum[idx] = sum;
    if (c == 0) {
        float bs = 0.f;
        for (int h = 0; h < HEADS; ++h)
            bs += b_in[EDIM + h * HDIM + d];
        bksum[d] = bs;
    }
}

// ---------------------------------------------------------------------------
// K1: tiled f32 GEMM: out[n, j] = query[n,:] . Wsel[j,:]  (j in [0,288))
//   j <  256 : Wsel = W_in[j], result -> q[n,j]   = (dot + b_in[j]) * SCALING
//   j >= 256 : Wsel = Wksum[j-256], result -> khs[n,j-256] = dot + bksum
// BM=BN=64, BK=16, 256 threads, 4x4 per thread.
// ---------------------------------------------------------------------------
__global__ __launch_bounds__(256) void qk_gemm(const float* __restrict__ query,
                                               const float* __restrict__ W_in,
                                               const float* __restrict__ b_in,
                                               const float* __restrict__ Wksum,
                                               const float* __restrict__ bksum,
                                               float* __restrict__ q_out,
                                               float* __restrict__ khs_out) {
    __shared__ float As[64][17];
    __shared__ float Bs[16][65];

    int row0 = blockIdx.x * 64;
    int j0   = blockIdx.y * 64;
    int t    = threadIdx.x;
    int tx = t & 15, ty = t >> 4;

    float acc[4][4];
#pragma unroll
    for (int i = 0; i < 4; ++i)
#pragma unroll
        for (int j = 0; j < 4; ++j) acc[i][j] = 0.f;

    int lm  = t >> 2;          // 0..63 row (A) / j (B)
    int lk4 = (t & 3) * 4;     // 0,4,8,12

    for (int k0 = 0; k0 < EDIM; k0 += 16) {
        // load A tile
        {
            const float4 a = *(const float4*)(query + (size_t)(row0 + lm) * EDIM + k0 + lk4);
            As[lm][lk4 + 0] = a.x; As[lm][lk4 + 1] = a.y;
            As[lm][lk4 + 2] = a.z; As[lm][lk4 + 3] = a.w;
        }
        // load B tile (transposed store)
        {
            int jglob = j0 + lm;
            float4 b = make_float4(0.f, 0.f, 0.f, 0.f);
            if (jglob < 288) {
                const float* wrow = (jglob < 256)
                    ? (W_in + (size_t)jglob * EDIM)
                    : (Wksum + (size_t)(jglob - 256) * EDIM);
                b = *(const float4*)(wrow + k0 + lk4);
            }
            Bs[lk4 + 0][lm] = b.x; Bs[lk4 + 1][lm] = b.y;
            Bs[lk4 + 2][lm] = b.z; Bs[lk4 + 3][lm] = b.w;
        }
        __syncthreads();
#pragma unroll
        for (int kk = 0; kk < 16; ++kk) {
            float a[4], b[4];
#pragma unroll
            for (int i = 0; i < 4; ++i) a[i] = As[ty * 4 + i][kk];
#pragma unroll
            for (int j = 0; j < 4; ++j) b[j] = Bs[kk][tx * 4 + j];
#pragma unroll
            for (int i = 0; i < 4; ++i)
#pragma unroll
                for (int j = 0; j < 4; ++j)
                    acc[i][j] = fmaf(a[i], b[j], acc[i][j]);
        }
        __syncthreads();
    }

#pragma unroll
    for (int i = 0; i < 4; ++i) {
        int row = row0 + ty * 4 + i;
#pragma unroll
        for (int j = 0; j < 4; ++j) {
            int jglob = j0 + tx * 4 + j;
            if (jglob < 256) {
                q_out[(size_t)row * EDIM + jglob] = (acc[i][j] + b_in[jglob]) * SCALING;
            } else if (jglob < 288) {
                int d = jglob - 256;
                khs_out[(size_t)row * HDIM + d] = acc[i][j] + bksum[d];
            }
        }
    }
}

// ---------------------------------------------------------------------------
// K3: per-edge: edge_attn[h,e] = q[dst,h,:].khs[src,:] + bias[h,e]
//     atomicAdd into col[h, src]; mark touched[src].
// One wave (64 lanes) per edge; lane i holds q elems 4i..4i+3 (head = i>>3).
// ---------------------------------------------------------------------------
__global__ __launch_bounds__(256) void edge_kernel(const float* __restrict__ q,
                                                   const float* __restrict__ khs,
                                                   const int* __restrict__ edge_index,
                                                   const float* __restrict__ bias,
                                                   float* __restrict__ col,
                                                   int* __restrict__ touched) {
    int gtid   = blockIdx.x * blockDim.x + threadIdx.x;
    int wave   = gtid >> 6;
    int lane   = threadIdx.x & 63;
    int nwaves = (gridDim.x * blockDim.x) >> 6;

    for (int e = wave; e < NEDGE; e += nwaves) {
        int src = edge_index[e];
        int dst = edge_index[NEDGE + e];
        const float4 qv = *(const float4*)(q + (size_t)dst * EDIM + lane * 4);
        const float4 kv = *(const float4*)(khs + (size_t)src * HDIM + (lane & 7) * 4);
        float p = qv.x * kv.x + qv.y * kv.y + qv.z * kv.z + qv.w * kv.w;
        p += __shfl_xor(p, 1);
        p += __shfl_xor(p, 2);
        p += __shfl_xor(p, 4);
        if ((lane & 7) == 0) {
            int h = lane >> 3;
            float val = p + bias[(size_t)h * NEDGE + e];
            atomicAdd(col + (size_t)h * N_NODES + src, val);
            if (h == 0) touched[src] = 1;
        }
    }
}

// ---------------------------------------------------------------------------
// K4a: per-head softmax over nodes. attn[h,n] = softmax(col[h,:] with -inf
//      where !touched)
// ---------------------------------------------------------------------------
__global__ __launch_bounds__(256) void softmax_kernel(const float* __restrict__ col,
                                                      const int* __restrict__ touched,
                                                      float* __restrict__ attn) {
    int h = blockIdx.x;
    const float* c = col + (size_t)h * N_NODES;
    float* a = attn + (size_t)h * N_NODES;
    __shared__ float red[256];
    int t = threadIdx.x;

    float m = -INFINITY;
    for (int n = t; n < N_NODES; n += 256)
        if (touched[n]) m = fmaxf(m, c[n]);
    red[t] = m; __syncthreads();
    for (int st = 128; st; st >>= 1) {
        if (t < st) red[t] = fmaxf(red[t], red[t + st]);
        __syncthreads();
    }
    m = red[0]; __syncthreads();

    float sum = 0.f;
    for (int n = t; n < N_NODES; n += 256) {
        float e = touched[n] ? expf(c[n] - m) : 0.f;
        a[n] = e;
        sum += e;
    }
    red[t] = sum; __syncthreads();
    for (int st = 128; st; st >>= 1) {
        if (t < st) red[t] += red[t + st];
        __syncthreads();
    }
    float inv = 1.f / red[0];
    for (int n = t; n < N_NODES; n += 256)
        a[n] *= inv;
}

// ---------------------------------------------------------------------------
// K4b: s[h, c] = sum_n attn[h,n] * query[n, c]   (skip all-zero node chunks)
// grid (32 chunks, 8 heads), 256 threads; thread owns column c.
// ---------------------------------------------------------------------------
__global__ __launch_bounds__(256) void sweight_kernel(const float* __restrict__ attn,
                                                      const float* __restrict__ query,
                                                      float* __restrict__ s) {
    int h = blockIdx.y;
    int n0 = blockIdx.x * 256;
    int t = threadIdx.x;
    __shared__ float aw[256];
    __shared__ float red[256];

    float w = attn[(size_t)h * N_NODES + n0 + t];
    aw[t] = w;
    red[t] = w;
    __syncthreads();
    for (int st = 128; st; st >>= 1) {
        if (t < st) red[t] = fmaxf(red[t], red[t + st]);
        __syncthreads();
    }
    if (red[0] == 0.f) return;   // whole chunk contributes exactly nothing

    float acc = 0.f;
    for (int n = 0; n < 256; ++n) {
        float wn = aw[n];                      // uniform across block
        if (wn != 0.f)
            acc = fmaf(wn, query[(size_t)(n0 + n) * EDIM + t], acc);
    }
    atomicAdd(s + (size_t)h * EDIM + t, acc);
}

// ---------------------------------------------------------------------------
// K5: out_flat[j] = s[j>>5,:] . W_in[512+j,:] + b_in[512+j]
//     r[i] = W_out[i,:] . out_flat + b_out[i]
// single block of 256 threads.
// ---------------------------------------------------------------------------
__global__ __launch_bounds__(256) void final_kernel(const float* __restrict__ s,
                                                    const float* __restrict__ W_in,
                                                    const float* __restrict__ b_in,
                                                    const float* __restrict__ W_out,
                                                    const float* __restrict__ b_out,
                                                    float* __restrict__ r) {
    __shared__ float of[256];
    int j = threadIdx.x;
    int h = j >> 5;
    const float* wrow = W_in + (size_t)(2 * EDIM + j) * EDIM;
    const float* sh = s + (size_t)h * EDIM;
    float acc = b_in[2 * EDIM + j];
    for (int c = 0; c < EDIM; ++c) acc = fmaf(sh[c], wrow[c], acc);
    of[j] = acc;
    __syncthreads();
    const float* wo = W_out + (size_t)j * EDIM;
    float acc2 = b_out[j];
    for (int c = 0; c < EDIM; ++c) acc2 = fmaf(wo[c], of[c], acc2);
    r[j] = acc2;
}

// ---------------------------------------------------------------------------
// K6: broadcast row r to all N rows of out.
// ---------------------------------------------------------------------------
__global__ __launch_bounds__(256) void bcast_kernel(const float* __restrict__ r,
                                                    float* __restrict__ out) {
    int idx = blockIdx.x * blockDim.x + threadIdx.x;   // over N*E/4
    const float4* r4 = (const float4*)r;
    ((float4*)out)[idx] = r4[idx & 63];
}

// ---------------------------------------------------------------------------
extern "C" void kernel_launch(void* const* d_in, const int* in_sizes, int n_in,
                              void* d_out, int out_size, void* d_ws, size_t ws_size,
                              hipStream_t stream) {
    const float* query     = (const float*)d_in[0];
    const int*   edge_idx  = (const int*)d_in[1];
    const float* attn_bias = (const float*)d_in[2];
    const float* W_in      = (const float*)d_in[3];
    const float* b_in      = (const float*)d_in[4];
    const float* W_out     = (const float*)d_in[5];
    const float* b_out     = (const float*)d_in[6];
    float* out = (float*)d_out;
    float* ws  = (float*)d_ws;

    float* q       = ws;                          // 2097152
    float* khs     = q + 2097152;                 // 262144
    float* Wksum   = khs + 262144;                // 8192
    float* bksum   = Wksum + 8192;                // 64 (32 used)
    float* col     = bksum + 64;                  // 65536
    int*   touched = (int*)(col + 65536);         // 8192
    float* attn    = (float*)(touched + 8192);    // 65536
    float* s       = attn + 65536;                // 2048
    float* r       = s + 2048;                    // 256

    // zero accumulators: col, touched, attn, s  (contiguous region)
    hipMemsetAsync(col, 0, (size_t)(65536 + 8192 + 65536 + 2048) * sizeof(float), stream);

    wksum_kernel<<<32, 256, 0, stream>>>(W_in, b_in, Wksum, bksum);

    dim3 g1(N_NODES / 64, 5);
    qk_gemm<<<g1, 256, 0, stream>>>(query, W_in, b_in, Wksum, bksum, q, khs);

    edge_kernel<<<2048, 256, 0, stream>>>(q, khs, edge_idx, attn_bias, col, touched);

    softmax_kernel<<<HEADS, 256, 0, stream>>>(col, touched, attn);

    dim3 g4(N_NODES / 256, HEADS);
    sweight_kernel<<<g4, 256, 0, stream>>>(attn, query, s);

    final_kernel<<<1, 256, 0, stream>>>(s, W_in, b_in, W_out, b_out, r);

    bcast_kernel<<<(N_NODES * EDIM / 4) / 256, 256, 0, stream>>>(r, out);
}